// Round 9
// baseline (221.023 us; speedup 1.0000x reference)
//
#include <hip/hip_runtime.h>
#include <hip/hip_bf16.h>
#include <hip/hip_fp16.h>

#define BB 8
#define CC 128
#define HH 64
#define WW 64
#define OO 128
#define NJ 18
#define HW 4096

typedef unsigned short u16;
typedef unsigned int u32;
typedef __attribute__((ext_vector_type(8))) _Float16 f16x8;
typedef __attribute__((ext_vector_type(4))) float f32x4;

__device__ __forceinline__ u32 pk2h(float a, float b) {
    union { __half2 h; u32 u; } cv;
    cv.h = __float22half2_rn(make_float2(a, b));   // v_cvt_pk_f16_f32
    return cv.u;
}
__device__ __forceinline__ u16 f2h(float f) {
    union { __half h; u16 u; } cv;
    cv.h = __float2half_rn(f);
    return cv.u;
}

// ---------------------------------------------------------------------------
// k_pre: (a) x fp32 [b][c][hw] -> xT f16 [b][hw][c]; (b) weight prep wT/wA
//        as f16. Structure identical to the proven bf16 version; only the
//        pack intrinsic changed. f16 beats bf16 precision for N(0,1) data.
// ---------------------------------------------------------------------------
__global__ __launch_bounds__(256)
void k_pre(const float* __restrict__ x, u16* __restrict__ xT,
           const float* __restrict__ w_def, const float* __restrict__ w_off,
           u16* __restrict__ wT, u16* __restrict__ wA) {
    __shared__ float tile[64][129];
    const int t = threadIdx.x;
    if (blockIdx.x < 512) {
        const int b = blockIdx.x >> 6;
        const int hw0 = (blockIdx.x & 63) << 6;
        const float* xb = x + (size_t)b * CC * HW + hw0;
        const int tw = t & 63, tc = t >> 6;
#pragma unroll
        for (int r = 0; r < 32; ++r) {
            int c = r * 4 + tc;                 // wave-uniform
            tile[tw][c] = xb[c * HW + tw];
        }
        __syncthreads();
        u16* dst = xT + ((size_t)b * HW + hw0) * CC;
#pragma unroll
        for (int r = 0; r < 4; ++r) {
            int item = t + (r << 8);            // 1024 items = 64 hw x 16 segs
            int seg = item & 15, hw = item >> 4;
            union { u32 d[4]; uint4 v; } p;
#pragma unroll
            for (int i = 0; i < 4; ++i)
                p.d[i] = pk2h(tile[hw][seg * 8 + 2 * i], tile[hw][seg * 8 + 2 * i + 1]);
            *(uint4*)&dst[hw * CC + seg * 8] = p.v;
        }
    } else {
        int idx = (blockIdx.x - 512) * 256 + t;
        if (idx < 9 * OO * CC) {
            int c = idx & 127, o = (idx >> 7) & 127, kk = idx >> 14;
            wT[idx] = f2h(w_def[(o * CC + c) * 9 + kk]);
        }
        if (idx < 32 * 1152) {
            int k = idx % 1152, j = idx / 1152;
            int q = k >> 7, c = k & 127;
            wA[idx] = (j < NJ) ? f2h(w_off[(j * CC + c) * 9 + q]) : (u16)0;
        }
    }
}

// ---------------------------------------------------------------------------
// k_off: offset conv via MFMA (f16 now), M=18(->32), N=64, K=1152.
// Round-0-proven structure; only the MFMA dtype changed.
// ---------------------------------------------------------------------------
__global__ __launch_bounds__(256, 2)
void k_off(const u16* __restrict__ xT, const u16* __restrict__ wA,
           const float* __restrict__ b_off, float* __restrict__ offs) {
    __shared__ u16 s_x[198 * 128];   // [3 rows x 66 w][128 c] swizzled
    const int t = threadIdx.x, lane = t & 63, wv = t >> 6;
    const int posl = lane & 15, kg = lane >> 4;
    const int b = blockIdx.x & 7, h = blockIdx.x >> 3;

    for (int it = t; it < 3168; it += 256) {
        int seg = it & 15, pix = it >> 4;       // pix = r*66 + wp
        int r = pix / 66, wp = pix - r * 66;
        int y = h - 1 + r, w = wp - 1;
        uint4 v = make_uint4(0, 0, 0, 0);
        if (y >= 0 && y < HH && w >= 0 && w < WW)
            v = *(const uint4*)&xT[((size_t)(b * HW) + y * WW + w) * CC + seg * 8];
        *(uint4*)&s_x[pix * 128 + ((seg ^ (pix & 15)) * 8)] = v;
    }
    __syncthreads();

    f32x4 acc0 = {0.f, 0.f, 0.f, 0.f}, acc1 = {0.f, 0.f, 0.f, 0.f};
    for (int q = 0; q < 9; ++q) {
        int qy = q / 3, qx = q - qy * 3;
        int pix = qy * 66 + (wv * 16 + posl) + qx;
        int prow = pix * 128, pxor = pix & 15;
#pragma unroll
        for (int ki = 0; ki < 4; ++ki) {
            int ks = q * 4 + ki;
            int cidx = ki * 4 + kg;
            f16x8 bfr = *(const f16x8*)&s_x[prow + ((cidx ^ pxor) * 8)];
            f16x8 a0 = *(const f16x8*)&wA[posl * 1152 + ks * 32 + kg * 8];
            f16x8 a1 = *(const f16x8*)&wA[(16 + posl) * 1152 + ks * 32 + kg * 8];
            acc0 = __builtin_amdgcn_mfma_f32_16x16x32_f16(a0, bfr, acc0, 0, 0, 0);
            acc1 = __builtin_amdgcn_mfma_f32_16x16x32_f16(a1, bfr, acc1, 0, 0, 0);
        }
    }
    const int pos = wv * 16 + posl;
#pragma unroll
    for (int r = 0; r < 4; ++r) {
        int j = kg * 4 + r;
        offs[(b * NJ + j) * HW + h * WW + pos] = acc0[r] + b_off[j];
    }
#pragma unroll
    for (int r = 0; r < 4; ++r) {
        int j = 16 + kg * 4 + r;
        if (j < NJ) offs[(b * NJ + j) * HW + h * WW + pos] = acc1[r] + b_off[j];
    }
}

// ---------------------------------------------------------------------------
// k_main v9: f16 packed-math interp + max-TLP in-register structure.
// Calibrated model (r8): effective clock ~1 GHz -> VALU-issue + latency are
// the binders. Fixes: (1) interp via __hmul2/__hfma2 on packed f16 pairs:
// 17 VALU ops/u32 -> 4 (the dominant VALU phase, ~4x cut); (2) 16 waves/CU:
// grid 1024 (b, h, half-row), 4 blocks/CU, LDS = 4.6 KB coord table only,
// launch_bounds(256,4) caps VGPR at 128. Gather->A-fragment path is the
// r5/r6-PROVEN per-lane mapping (lane (posl,kg): pos p0l+posl, channels
// ks*32+kg*8+{0..7}); gathers done in ks-pairs to bound live registers.
// No barriers in the kk loop. MFMA/epilogue r6/r8-verbatim semantics.
// ---------------------------------------------------------------------------
__global__ __launch_bounds__(256, 4)
void k_main(const u16* __restrict__ xT, const float* __restrict__ offs,
            const u16* __restrict__ wT, const float* __restrict__ b_def,
            float* __restrict__ out) {
    __shared__ __align__(16) u16 s_coord[4608];   // 288 entries x 32 B

    const int t = threadIdx.x, lane = t & 63, wv = t >> 6;   // wv 0..3
    const int posl = lane & 15, kg = lane >> 4;
    const int bid = blockIdx.x;
    const int b = bid & 7, rest = bid >> 3;
    const int h = rest >> 1, half = rest & 1;
    const int pos0 = half * 32;
    const char* xb = (const char*)xT + (size_t)b * (HW * CC * 2);

    // ---- coord table: 9 kk x 32 pos, proven arithmetic (r8 verbatim) ----
    for (int e = t; e < 288; e += 256) {
        const int kk = e >> 5, pl = e & 31;
        const int pw = pos0 + pl;
        const float oy = offs[(b * NJ + 2 * kk) * HW + h * WW + pw];
        const float ox = offs[(b * NJ + 2 * kk + 1) * HW + h * WW + pw];
        const int ky = kk / 3, kx = kk - ky * 3;
        float py = (float)(h - 1 + ky) + oy;
        float px = (float)(pw - 1 + kx) + ox;
        float fy = floorf(py), fx = floorf(px);
        int iy0 = (int)fy, ix0 = (int)fx;
        float wy = py - fy, wx = px - fx;
        int iy1 = iy0 + 1, ix1 = ix0 + 1;
        float my0 = (iy0 >= 0 && iy0 < HH) ? 1.0f : 0.0f;
        float my1 = (iy1 >= 0 && iy1 < HH) ? 1.0f : 0.0f;
        float mx0 = (ix0 >= 0 && ix0 < WW) ? 1.0f : 0.0f;
        float mx1 = (ix1 >= 0 && ix1 < WW) ? 1.0f : 0.0f;
        int iy0c = min(max(iy0, 0), HH - 1), iy1c = min(max(iy1, 0), HH - 1);
        int ix0c = min(max(ix0, 0), WW - 1), ix1c = min(max(ix1, 0), WW - 1);
        float wy1 = 1.0f - wy, wx1 = 1.0f - wx;
        float4 cw = make_float4(my0 * mx0 * wy1 * wx1, my0 * mx1 * wy1 * wx,
                                my1 * mx0 * wy  * wx1, my1 * mx1 * wy  * wx);
        int4 co = make_int4((iy0c * WW + ix0c) << 8, (iy0c * WW + ix1c) << 8,
                            (iy1c * WW + ix0c) << 8, (iy1c * WW + ix1c) << 8);
        *(int4*)&s_coord[e * 16] = co;
        *(float4*)&s_coord[e * 16 + 8] = cw;
    }
    __syncthreads();

    const int p0l = (wv >> 1) * 16;      // wave's pos_local base (0 or 16)
    const int oh = wv & 1;               // o-half
    const int mypl = p0l + posl;         // this lane's pos_local

    f32x4 acc[4];
#pragma unroll
    for (int ot = 0; ot < 4; ++ot) acc[ot] = (f32x4){0.f, 0.f, 0.f, 0.f};

#pragma unroll
    for (int kk = 0; kk < 9; ++kk) {
        const int4   co  = *(const int4*)&s_coord[(kk * 32 + mypl) * 16];
        const float4 cwf = *(const float4*)&s_coord[(kk * 32 + mypl) * 16 + 8];
        const __half2 w0 = __float2half2_rn(cwf.x);
        const __half2 w1 = __float2half2_rn(cwf.y);
        const __half2 w2 = __float2half2_rn(cwf.z);
        const __half2 w3 = __float2half2_rn(cwf.w);

        f16x8 A[4];
#pragma unroll
        for (int ksp = 0; ksp < 2; ++ksp) {
            // gather 2 K-chunks x 4 corners (16B each), lane's own channels
            uint4 g[2][4];
#pragma unroll
            for (int ks2 = 0; ks2 < 2; ++ks2) {
                const int sb = (ksp * 2 + ks2) * 64 + kg * 16;
                g[ks2][0] = *(const uint4*)(xb + co.x + sb);
                g[ks2][1] = *(const uint4*)(xb + co.y + sb);
                g[ks2][2] = *(const uint4*)(xb + co.z + sb);
                g[ks2][3] = *(const uint4*)(xb + co.w + sb);
            }
            // packed-f16 interp: 4 ops per u32 (2 channels)
#pragma unroll
            for (int ks2 = 0; ks2 < 2; ++ks2) {
                const u32* u00 = (const u32*)&g[ks2][0];
                const u32* u01 = (const u32*)&g[ks2][1];
                const u32* u10 = (const u32*)&g[ks2][2];
                const u32* u11 = (const u32*)&g[ks2][3];
                union { u32 d[4]; f16x8 v; } pk;
#pragma unroll
                for (int i = 0; i < 4; ++i) {
                    union { u32 u; __half2 h; } c0, c1, c2, c3, r;
                    c0.u = u00[i]; c1.u = u01[i]; c2.u = u10[i]; c3.u = u11[i];
                    __half2 s = __hmul2(c0.h, w0);
                    s = __hfma2(c1.h, w1, s);
                    s = __hfma2(c2.h, w2, s);
                    s = __hfma2(c3.h, w3, s);
                    r.h = s;
                    pk.d[i] = r.u;
                }
                A[ksp * 2 + ks2] = pk.v;
            }
        }

        // ---- GEMM (r6/r8-verbatim semantics, f16 weights) ----
        const u16* wkk = wT + kk * (OO * CC);
#pragma unroll
        for (int ks = 0; ks < 4; ++ks)
#pragma unroll
            for (int ot = 0; ot < 4; ++ot) {
                f16x8 wfr = *(const f16x8*)
                    &wkk[(oh * 64 + ot * 16 + posl) * CC + ks * 32 + kg * 8];
                acc[ot] = __builtin_amdgcn_mfma_f32_16x16x32_f16(
                    A[ks], wfr, acc[ot], 0, 0, 0);
            }
    }

    // ---- epilogue (proven): D col = o, row = pos = pos0+p0l+kg*4+r ----
    const int wbase = pos0 + p0l;
#pragma unroll
    for (int ot = 0; ot < 4; ++ot) {
        const int o = oh * 64 + ot * 16 + posl;
        const float bd = b_def[o];
        float4 res;
        res.x = acc[ot][0] + bd;
        res.y = acc[ot][1] + bd;
        res.z = acc[ot][2] + bd;
        res.w = acc[ot][3] + bd;
        *(float4*)&out[((b * OO + o) * HH + h) * WW + wbase + kg * 4] = res;
    }
}

extern "C" void kernel_launch(void* const* d_in, const int* in_sizes, int n_in,
                              void* d_out, int out_size, void* d_ws, size_t ws_size,
                              hipStream_t stream) {
    const float* x     = (const float*)d_in[0];
    const float* w_off = (const float*)d_in[1];
    const float* b_off = (const float*)d_in[2];
    const float* w_def = (const float*)d_in[3];
    const float* b_def = (const float*)d_in[4];
    float* out = (float*)d_out;

    float* offs = (float*)d_ws;                  // 8*18*4096 f32 = 2.36 MB
    u16*   xT   = (u16*)(offs + BB * NJ * HW);   // 8*4096*128    = 8.39 MB
    u16*   wT   = xT + (size_t)BB * HW * CC;     // 9*128*128     = 0.29 MB
    u16*   wA   = wT + 9 * OO * CC;              // 32*1152       = 0.07 MB

    k_pre <<<1088, 256, 0, stream>>>(x, xT, w_def, w_off, wT, wA);
    k_off <<< 512, 256, 0, stream>>>(xT, wA, b_off, offs);
    k_main<<<1024, 256, 0, stream>>>(xT, offs, wT, b_def, out);
}

// Round 10
// 139.031 us; speedup vs baseline: 1.5897x; 1.5897x over previous
//
#include <hip/hip_runtime.h>
#include <hip/hip_bf16.h>

#define BB 8
#define CC 128
#define HH 64
#define WW 64
#define OO 128
#define NJ 18
#define HW 4096

typedef unsigned short u16;
typedef unsigned int u32;
typedef __attribute__((ext_vector_type(8))) __bf16 bf16x8;
typedef __attribute__((ext_vector_type(4))) float f32x4;

__device__ __forceinline__ u16 f2bf(float f) {
    u32 u = __float_as_uint(f);
    u += 0x7fffu + ((u >> 16) & 1u);   // RNE
    return (u16)(u >> 16);
}
__device__ __forceinline__ float bflo(u32 u) { return __uint_as_float(u << 16); }
__device__ __forceinline__ float bfhi(u32 u) { return __uint_as_float(u & 0xffff0000u); }
__device__ __forceinline__ u32 pk2bf(float s0, float s1) {
    union { __hip_bfloat162 h; u32 u; } cv;
    cv.h = __float22bfloat162_rn(make_float2(s0, s1));   // v_cvt_pk_bf16_f32
    return cv.u;
}

// ---------------------------------------------------------------------------
// k_pre (r1-verbatim, passing at 128.1 total): fused (a) x fp32 -> xT bf16
// channels-last transpose and (b) weight prep. Blocks [0,512) do xT,
// [512,1088) do prep; independent jobs run concurrently in one launch.
// ---------------------------------------------------------------------------
__global__ __launch_bounds__(256)
void k_pre(const float* __restrict__ x, u16* __restrict__ xT,
           const float* __restrict__ w_def, const float* __restrict__ w_off,
           u16* __restrict__ wT, u16* __restrict__ wA) {
    __shared__ float tile[64][129];
    const int t = threadIdx.x;
    if (blockIdx.x < 512) {
        const int b = blockIdx.x >> 6;
        const int hw0 = (blockIdx.x & 63) << 6;
        const float* xb = x + (size_t)b * CC * HW + hw0;
        const int tw = t & 63, tc = t >> 6;
#pragma unroll
        for (int r = 0; r < 32; ++r) {
            int c = r * 4 + tc;                 // wave-uniform
            tile[tw][c] = xb[c * HW + tw];
        }
        __syncthreads();
        u16* dst = xT + ((size_t)b * HW + hw0) * CC;
#pragma unroll
        for (int r = 0; r < 4; ++r) {
            int item = t + (r << 8);            // 1024 items = 64 hw x 16 segs
            int seg = item & 15, hw = item >> 4;
            union { u32 d[4]; uint4 v; } p;
#pragma unroll
            for (int i = 0; i < 4; ++i)
                p.d[i] = pk2bf(tile[hw][seg * 8 + 2 * i], tile[hw][seg * 8 + 2 * i + 1]);
            *(uint4*)&dst[hw * CC + seg * 8] = p.v;
        }
    } else {
        int idx = (blockIdx.x - 512) * 256 + t;
        if (idx < 9 * OO * CC) {
            int c = idx & 127, o = (idx >> 7) & 127, kk = idx >> 14;
            wT[idx] = f2bf(w_def[(o * CC + c) * 9 + kk]);
        }
        if (idx < 32 * 1152) {
            int k = idx % 1152, j = idx / 1152;
            int q = k >> 7, c = k & 127;
            wA[idx] = (j < NJ) ? f2bf(w_off[(j * CC + c) * 9 + q]) : (u16)0;
        }
    }
}

// ---------------------------------------------------------------------------
// k_fused (r2-verbatim, best-measured main kernel: 67.5 us across 5
// dispatches): 512 threads (8 waves), fused offset-conv + sample + GEMM.
// Session post-mortem: this structure's gather mapping (gpos=t>>3,
// segsub=t&7: quarter-wave = 2 corner rows x 128B contiguous, ~4 cache
// lines/QW) is near the scattered-VMEM serialization optimum; five
// structural attacks (reg-pipeline r3, barrier-free r4/r5, split r6,
// async-DMA r8, packed-f16+occupancy r9) all measured worse.
// ---------------------------------------------------------------------------
__global__ __launch_bounds__(512, 4)
void k_fused(const u16* __restrict__ xT, const u16* __restrict__ wA,
             const float* __restrict__ b_off, const u16* __restrict__ wT,
             const float* __restrict__ b_def, float* __restrict__ out) {
    __shared__ __align__(16) u16 smem[25344];   // 50,688 B multi-phase
    u16*   s_x    = smem;                       // [3 rows x 66 w][128 c] swz
    float* s_off  = (float*)smem;               // [18][64]
    u16*   s_samp = smem + 4096;                // byte offset 8192, [2][8192]

    const int t = threadIdx.x, lane = t & 63, wv = t >> 6;   // wv 0..7
    const int posl = lane & 15, kg = lane >> 4;
    const int b = blockIdx.x & 7, h = blockIdx.x >> 3;
    const char* xb = (const char*)xT + (size_t)b * (HW * CC * 2);

    // ================= phase 1: offset conv ==============================
    for (int it = t; it < 3168; it += 512) {
        int seg = it & 15, pix = it >> 4;       // pix = r*66 + wp
        int r = pix / 66, wp = pix - r * 66;
        int y = h - 1 + r, w = wp - 1;
        uint4 v = make_uint4(0, 0, 0, 0);
        if (y >= 0 && y < HH && w >= 0 && w < WW)
            v = *(const uint4*)&xT[((size_t)(b * HW) + y * WW + w) * CC + seg * 8];
        *(uint4*)&s_x[pix * 128 + ((seg ^ (pix & 15)) * 8)] = v;
    }
    __syncthreads();

    {
        // 8 waves: jg picks j-halves [0,16) / [16,32) (wA zero-padded to 32),
        // wq picks the 16-position quarter.
        const int jg = wv >> 2, wq = wv & 3;
        f32x4 acc0 = {0.f, 0.f, 0.f, 0.f};
        for (int qq = 0; qq < 9; ++qq) {
            int qy = qq / 3, qx = qq - qy * 3;
            int pix = qy * 66 + (wq * 16 + posl) + qx;
            int prow = pix * 128, pxr = pix & 15;
#pragma unroll
            for (int ki = 0; ki < 4; ++ki) {
                int ks = qq * 4 + ki;
                int cidx = ki * 4 + kg;
                bf16x8 bfr = *(const bf16x8*)&s_x[prow + ((cidx ^ pxr) * 8)];
                bf16x8 a0 = *(const bf16x8*)&wA[(jg * 16 + posl) * 1152 + ks * 32 + kg * 8];
                acc0 = __builtin_amdgcn_mfma_f32_16x16x32_bf16(a0, bfr, acc0, 0, 0, 0);
            }
        }
        __syncthreads();   // all s_x reads done before s_off aliases it
        const int pos = wq * 16 + posl;
#pragma unroll
        for (int r = 0; r < 4; ++r) {
            int j = jg * 16 + kg * 4 + r;
            if (j < NJ) s_off[j * 64 + pos] = acc0[r] + b_off[j];
        }
    }
    __syncthreads();

    // ================= main: sample + GEMM ===============================
    const int gpos = t >> 3;             // 0..63 (= w)
    const int segsub = t & 7;            // 0..7
    const int pxor = gpos & 15;
    const int slotbase = gpos * 128;
    const int mgrp = wv >> 2;            // M half: mt in {2*mgrp, 2*mgrp+1}
    const int wvn = wv & 3;              // N quarter: o0 = wvn*32

    // preload all 18 offset values into registers (from LDS)
    float oyv[9], oxv[9];
#pragma unroll
    for (int kk = 0; kk < 9; ++kk) {
        oyv[kk] = s_off[(2 * kk) * 64 + gpos];
        oxv[kk] = s_off[(2 * kk + 1) * 64 + gpos];
    }

    auto coords = [&](int kk, float oy, float ox, float4& cw, int4& co) {
        int ky = kk / 3, kx = kk - ky * 3;
        float py = (float)(h - 1 + ky) + oy;
        float px = (float)(gpos - 1 + kx) + ox;
        float fy = floorf(py), fx = floorf(px);
        int iy0 = (int)fy, ix0 = (int)fx;
        float wy = py - fy, wx = px - fx;
        int iy1 = iy0 + 1, ix1 = ix0 + 1;
        float my0 = (iy0 >= 0 && iy0 < HH) ? 1.0f : 0.0f;
        float my1 = (iy1 >= 0 && iy1 < HH) ? 1.0f : 0.0f;
        float mx0 = (ix0 >= 0 && ix0 < WW) ? 1.0f : 0.0f;
        float mx1 = (ix1 >= 0 && ix1 < WW) ? 1.0f : 0.0f;
        int iy0c = min(max(iy0, 0), HH - 1), iy1c = min(max(iy1, 0), HH - 1);
        int ix0c = min(max(ix0, 0), WW - 1), ix1c = min(max(ix1, 0), WW - 1);
        float wy1 = 1.0f - wy, wx1 = 1.0f - wx;
        cw = make_float4(my0 * mx0 * wy1 * wx1, my0 * mx1 * wy1 * wx,
                         my1 * mx0 * wy  * wx1, my1 * mx1 * wy  * wx);
        co = make_int4((iy0c * WW + ix0c) << 8, (iy0c * WW + ix1c) << 8,
                       (iy1c * WW + ix0c) << 8, (iy1c * WW + ix1c) << 8);
    };
    auto issue_gather = [&](const int4 co, uint4 q[2][4]) {
#pragma unroll
        for (int j = 0; j < 2; ++j) {
            const int sb = (segsub + 8 * j) * 16;
            q[j][0] = *(const uint4*)(xb + co.x + sb);
            q[j][1] = *(const uint4*)(xb + co.y + sb);
            q[j][2] = *(const uint4*)(xb + co.z + sb);
            q[j][3] = *(const uint4*)(xb + co.w + sb);
        }
    };
    auto interp_store = [&](const float4 cw, uint4 q[2][4], int p) {
#pragma unroll
        for (int j = 0; j < 2; ++j) {
            const int seg = segsub + 8 * j;
            const u32* u00 = (const u32*)&q[j][0];
            const u32* u01 = (const u32*)&q[j][1];
            const u32* u10 = (const u32*)&q[j][2];
            const u32* u11 = (const u32*)&q[j][3];
            union { u32 d[4]; uint4 v; } pk;
#pragma unroll
            for (int i = 0; i < 4; ++i) {
                float s0 = cw.x * bflo(u00[i]) + cw.y * bflo(u01[i])
                         + cw.z * bflo(u10[i]) + cw.w * bflo(u11[i]);
                float s1 = cw.x * bfhi(u00[i]) + cw.y * bfhi(u01[i])
                         + cw.z * bfhi(u10[i]) + cw.w * bfhi(u11[i]);
                pk.d[i] = pk2bf(s0, s1);
            }
            *(uint4*)&s_samp[p * 8192 + slotbase + ((seg ^ pxor) * 8)] = pk.v;
        }
    };
    auto load_w = [&](int kk, bf16x8 wfr[4][2]) {
        const u16* wkk = wT + kk * (OO * CC);
        const int o0 = wvn * 32;
#pragma unroll
        for (int ct = 0; ct < 4; ++ct)
#pragma unroll
            for (int nt = 0; nt < 2; ++nt) {
                int o = o0 + nt * 16 + posl;
                wfr[ct][nt] = *(const bf16x8*)&wkk[o * CC + ct * 32 + kg * 8];
            }
    };

    f32x4 acc[2][2];
#pragma unroll
    for (int mtl = 0; mtl < 2; ++mtl) {
        acc[mtl][0] = (f32x4){0.f, 0.f, 0.f, 0.f};
        acc[mtl][1] = (f32x4){0.f, 0.f, 0.f, 0.f};
    }

    // ---- prolog: weights kk=0, samples kk=0 ----
    bf16x8 wA_[4][2], wB_[4][2];
    float4 cw; int4 co;
    uint4 q[2][4];
    load_w(0, wA_);
    coords(0, oyv[0], oxv[0], cw, co);
    issue_gather(co, q);
    interp_store(cw, q, 0);
    __syncthreads();

#pragma unroll
    for (int kk = 0; kk < 9; ++kk) {
        const int p = kk & 1;

        // ---- issue next kk's weight loads (first!) and gathers ----
        if (kk < 8) {
            load_w(kk + 1, wB_);
            coords(kk + 1, oyv[kk + 1], oxv[kk + 1], cw, co);
            issue_gather(co, q);
        }

        // ---- MFMA phase on samp[p]: weights already in registers ----
#pragma unroll
        for (int ct = 0; ct < 4; ++ct) {
            const int chunk = ct * 4 + kg;
#pragma unroll
            for (int mtl = 0; mtl < 2; ++mtl) {
                const int mt = mgrp * 2 + mtl;
                bf16x8 afr = *(const bf16x8*)
                    &s_samp[p * 8192 + (mt * 16 + posl) * 128 + ((chunk ^ posl) * 8)];
                acc[mtl][0] = __builtin_amdgcn_mfma_f32_16x16x32_bf16(
                    afr, wA_[ct][0], acc[mtl][0], 0, 0, 0);
                acc[mtl][1] = __builtin_amdgcn_mfma_f32_16x16x32_bf16(
                    afr, wA_[ct][1], acc[mtl][1], 0, 0, 0);
            }
        }

        // ---- consume prefetched corners -> samp[p^1]; single barrier ----
        if (kk < 8) {
            interp_store(cw, q, p ^ 1);
            __syncthreads();
        }

        // rotate weight buffers (renamed away by full unroll)
#pragma unroll
        for (int ct = 0; ct < 4; ++ct) {
            wA_[ct][0] = wB_[ct][0];
            wA_[ct][1] = wB_[ct][1];
        }
    }

    // ---- epilogue: D row = pos = mt*16 + kg*4 + r, col = o ----
#pragma unroll
    for (int nt = 0; nt < 2; ++nt) {
        const int o = wvn * 32 + nt * 16 + posl;
        const float bd = b_def[o];
        float* orow = out + ((b * OO + o) * HH + h) * WW;
#pragma unroll
        for (int mtl = 0; mtl < 2; ++mtl) {
            const int mt = mgrp * 2 + mtl;
            float4 res;
            res.x = acc[mtl][nt][0] + bd;
            res.y = acc[mtl][nt][1] + bd;
            res.z = acc[mtl][nt][2] + bd;
            res.w = acc[mtl][nt][3] + bd;
            *(float4*)&orow[mt * 16 + kg * 4] = res;
        }
    }
}

extern "C" void kernel_launch(void* const* d_in, const int* in_sizes, int n_in,
                              void* d_out, int out_size, void* d_ws, size_t ws_size,
                              hipStream_t stream) {
    const float* x     = (const float*)d_in[0];
    const float* w_off = (const float*)d_in[1];
    const float* b_off = (const float*)d_in[2];
    const float* w_def = (const float*)d_in[3];
    const float* b_def = (const float*)d_in[4];
    float* out = (float*)d_out;

    u16* xT = (u16*)d_ws;                        // 8*4096*128 bf16 = 8.39 MB
    u16* wT = xT + (size_t)BB * HW * CC;         // 9*128*128       = 0.29 MB
    u16* wA = wT + 9 * OO * CC;                  // 32*1152         = 0.07 MB

    k_pre  <<<1088, 256, 0, stream>>>(x, xT, w_def, w_off, wT, wA);
    k_fused<<< 512, 512, 0, stream>>>(xT, wA, b_off, wT, b_def, out);
}